// Round 1
// baseline (1139.133 us; speedup 1.0000x reference)
//
#include <hip/hip_runtime.h>
#include <hip/hip_bf16.h>
#include <math.h>

#define NL 4
#define DM 1024
#define DI 2048
#define RK 64
#define NS 16
#define LSEQ 1024
#define BATCH 2
#define MROWS (BATCH*LSEQ)   // 2048 rows for all GEMMs
#define NCHUNK 16
#define LC 64                // LSEQ / NCHUNK

typedef __attribute__((ext_vector_type(8))) short bf16x8;
typedef __attribute__((ext_vector_type(4))) float f32x4;
typedef __attribute__((ext_vector_type(4))) unsigned int u32x4;

__device__ __forceinline__ float bf2f(unsigned short u){
  union { unsigned int i; float f; } v; v.i = ((unsigned int)u) << 16; return v.f;
}
__device__ __forceinline__ unsigned short f2bf(float f){
  union { float f; unsigned int i; } v; v.f = f;
  unsigned int r = v.i + 0x7fffu + ((v.i >> 16) & 1u);  // RNE
  return (unsigned short)(r >> 16);
}
__device__ __forceinline__ float sigmoidf_(float x){ return 1.0f / (1.0f + __expf(-x)); }
__device__ __forceinline__ float softplusf_(float x){ return (x > 20.0f) ? x : log1pf(__expf(x)); }

// ---------------------------------------------------------------------------
// Generic bf16 MFMA GEMM:  C[m,n] = sum_k A[m,k] * W[n,k]
// A row-major [M,K] bf16, W row-major [N,K] bf16 (i.e. B^T layout).
// EPI: 0 = store bf16; 1 = atomicAdd fp32 (split-K); 2 = softplus(acc+bias[n]) fp32;
//      3 = fp32 +=(residual); 4 = store fp32
// ---------------------------------------------------------------------------
template<int BM, int BN, int WAVES_M, int WAVES_N, int EPI>
__global__ __launch_bounds__(256)
void gemm_bt(const unsigned short* __restrict__ A, const unsigned short* __restrict__ W,
             void* __restrict__ C, const float* __restrict__ bias,
             int M, int N, int K, int ldc, int kslices)
{
  constexpr int MT = BM / (WAVES_M * 16);
  constexpr int NT = BN / (WAVES_N * 16);
  constexpr int PAD = 40;   // padded k-stride (bf16 elems): 80B rows -> 2-way LDS conflicts only
  __shared__ __align__(16) unsigned short As[BM * PAD];
  __shared__ __align__(16) unsigned short Bs[BN * PAD];

  const int tid  = threadIdx.x;
  const int wave = tid >> 6;
  const int lane = tid & 63;
  const int wm   = wave / WAVES_N;
  const int wn   = wave % WAVES_N;
  const int quad = lane >> 4;
  const int l16  = lane & 15;

  const int m0 = blockIdx.x * BM;
  const int n0 = blockIdx.y * BN;
  const int Ks = K / kslices;
  const int kb = blockIdx.z * Ks;

  f32x4 acc[MT][NT];
  #pragma unroll
  for (int i = 0; i < MT; i++)
    #pragma unroll
    for (int j = 0; j < NT; j++)
      acc[i][j] = (f32x4){0.f, 0.f, 0.f, 0.f};

  for (int k0 = kb; k0 < kb + Ks; k0 += 32) {
    // ---- stage A tile [BM x 32] and W tile [BN x 32] into LDS (16B chunks)
    constexpr int ACH = (BM * 4 + 255) / 256;
    #pragma unroll
    for (int i = 0; i < ACH; i++) {
      int c = i * 256 + tid;
      if ((BM * 4) % 256 == 0 || c < BM * 4) {
        int row = c >> 2, kc = (c & 3) << 3;
        u32x4 v = *(const u32x4*)(A + (size_t)(m0 + row) * K + k0 + kc);
        *(u32x4*)(As + row * PAD + kc) = v;
      }
    }
    constexpr int BCH = (BN * 4 + 255) / 256;
    #pragma unroll
    for (int i = 0; i < BCH; i++) {
      int c = i * 256 + tid;
      if ((BN * 4) % 256 == 0 || c < BN * 4) {
        int row = c >> 2, kc = (c & 3) << 3;
        u32x4 v = *(const u32x4*)(W + (size_t)(n0 + row) * K + k0 + kc);
        *(u32x4*)(Bs + row * PAD + kc) = v;
      }
    }
    __syncthreads();

    bf16x8 af[MT], bfr[NT];
    #pragma unroll
    for (int mt = 0; mt < MT; mt++)
      af[mt] = *(const bf16x8*)(As + (wm * MT * 16 + mt * 16 + l16) * PAD + quad * 8);
    #pragma unroll
    for (int nt = 0; nt < NT; nt++)
      bfr[nt] = *(const bf16x8*)(Bs + (wn * NT * 16 + nt * 16 + l16) * PAD + quad * 8);
    #pragma unroll
    for (int mt = 0; mt < MT; mt++)
      #pragma unroll
      for (int nt = 0; nt < NT; nt++)
        acc[mt][nt] = __builtin_amdgcn_mfma_f32_16x16x32_bf16(af[mt], bfr[nt], acc[mt][nt], 0, 0, 0);
    __syncthreads();
  }

  // epilogue: D[m][n] with m = quad*4 + r, n = l16 (verified gfx950 C/D layout)
  #pragma unroll
  for (int mt = 0; mt < MT; mt++) {
    #pragma unroll
    for (int nt = 0; nt < NT; nt++) {
      int n = n0 + wn * NT * 16 + nt * 16 + l16;
      #pragma unroll
      for (int r = 0; r < 4; r++) {
        int m = m0 + wm * MT * 16 + mt * 16 + quad * 4 + r;
        float v = acc[mt][nt][r];
        size_t off = (size_t)m * ldc + n;
        if constexpr (EPI == 0)      ((unsigned short*)C)[off] = f2bf(v);
        else if constexpr (EPI == 1) atomicAdd((float*)C + off, v);
        else if constexpr (EPI == 2) ((float*)C)[off] = softplusf_(v + bias[n]);
        else if constexpr (EPI == 3) ((float*)C)[off] += v;
        else                         ((float*)C)[off] = v;
      }
    }
  }
}

// ---------------------------------------------------------------------------
__global__ __launch_bounds__(256)
void rmsnorm_kernel(const float* __restrict__ x, const float* __restrict__ w,
                    unsigned short* __restrict__ h)
{
  const int row = blockIdx.x;
  const float4 a = ((const float4*)(x + (size_t)row * DM))[threadIdx.x];
  float ss = a.x*a.x + a.y*a.y + a.z*a.z + a.w*a.w;
  #pragma unroll
  for (int o = 32; o > 0; o >>= 1) ss += __shfl_down(ss, o);
  __shared__ float red[4];
  if ((threadIdx.x & 63) == 0) red[threadIdx.x >> 6] = ss;
  __syncthreads();
  float rs = rsqrtf((red[0] + red[1] + red[2] + red[3]) * (1.0f / DM) + 1e-5f);
  const float4 wv = ((const float4*)w)[threadIdx.x];
  ushort4 o4;
  o4.x = f2bf(a.x * rs * wv.x);
  o4.y = f2bf(a.y * rs * wv.y);
  o4.z = f2bf(a.z * rs * wv.z);
  o4.w = f2bf(a.w * rs * wv.w);
  ((ushort4*)(h + (size_t)row * DM))[threadIdx.x] = o4;
}

// causal depthwise conv (width 4) + SiLU ; xi = xz[..., :DI]
__global__ __launch_bounds__(256)
void conv_silu_kernel(const unsigned short* __restrict__ xz,
                      const float* __restrict__ cw, const float* __restrict__ cb,
                      unsigned short* __restrict__ xc)
{
  int idx = blockIdx.x * 256 + threadIdx.x;        // [B, L, DI]
  int d = idx & (DI - 1);
  int t = (idx >> 11) & (LSEQ - 1);
  int b = idx >> 21;
  const float4 w4 = ((const float4*)cw)[d];
  const float wk[4] = {w4.x, w4.y, w4.z, w4.w};
  const unsigned short* xi = xz + (size_t)b * LSEQ * (2 * DI) + d;
  float acc = cb[d];
  #pragma unroll
  for (int k = 0; k < 4; k++) {
    int tt = t - 3 + k;
    if (tt >= 0) acc += bf2f(xi[(size_t)tt * (2 * DI)]) * wk[k];
  }
  xc[idx] = f2bf(acc * sigmoidf_(acc));
}

// dbc[:, :64] -> bf16 A-matrix for GEMM3
__global__ __launch_bounds__(256)
void extract_dt_kernel(const float* __restrict__ dbc, unsigned short* __restrict__ out)
{
  int idx = blockIdx.x * 256 + threadIdx.x;        // MROWS*RK
  int m = idx >> 6, r = idx & 63;
  out[idx] = f2bf(dbc[(size_t)m * 96 + r]);
}

__global__ void f32_to_bf16_kernel(const float* __restrict__ s, unsigned short* __restrict__ d, int n4)
{
  int i = blockIdx.x * 256 + threadIdx.x;
  int stride = gridDim.x * 256;
  for (; i < n4; i += stride) {
    float4 v = ((const float4*)s)[i];
    ushort4 o; o.x = f2bf(v.x); o.y = f2bf(v.y); o.z = f2bf(v.z); o.w = f2bf(v.w);
    ((ushort4*)d)[i] = o;
  }
}

// ---------------------------------------------------------------------------
// Chunked selective scan.  State layout for hend/hin: [b][chunk][n][d] (coalesced in d)
// ---------------------------------------------------------------------------
__global__ __launch_bounds__(256)
void scan1_kernel(const float* __restrict__ delta, const unsigned short* __restrict__ xc,
                  const float* __restrict__ dbc, const float* __restrict__ A_log,
                  float* __restrict__ hend, float* __restrict__ sumd)
{
  const int d = blockIdx.x * 256 + threadIdx.x;
  const int c = blockIdx.y;
  const int b = blockIdx.z;
  const int t0 = c * LC;
  __shared__ float bc[LC][32];                     // cols 0..15 = B, 16..31 = C
  #pragma unroll
  for (int i = 0; i < (LC * 32) / 256; i++) {
    int f = i * 256 + threadIdx.x;
    int r = f >> 5, col = f & 31;
    bc[r][col] = dbc[(size_t)(b * LSEQ + t0 + r) * 96 + 64 + col];
  }
  float Av[NS], h[NS];
  #pragma unroll
  for (int n = 0; n < NS; n++) { Av[n] = -__expf(A_log[(size_t)d * NS + n]); h[n] = 0.f; }
  __syncthreads();
  float sd = 0.f;
  for (int t = 0; t < LC; t++) {
    size_t ix = (size_t)(b * LSEQ + t0 + t) * DI + d;
    float dt = delta[ix];
    float xcv = bf2f(xc[ix]);
    sd += dt;
    float dx = dt * xcv;
    #pragma unroll
    for (int n = 0; n < NS; n++) {
      float da = __expf(dt * Av[n]);
      h[n] = da * h[n] + dx * bc[t][n];
    }
  }
  size_t base = ((size_t)(b * NCHUNK + c) * NS) * DI + d;
  #pragma unroll
  for (int n = 0; n < NS; n++) hend[base + (size_t)n * DI] = h[n];
  sumd[(size_t)(b * NCHUNK + c) * DI + d] = sd;
}

__global__ __launch_bounds__(256)
void scan2_kernel(const float* __restrict__ A_log, const float* __restrict__ hend,
                  const float* __restrict__ sumd, float* __restrict__ hin)
{
  int g = blockIdx.x * 256 + threadIdx.x;          // BATCH*DI threads
  int b = g >> 11;
  int d = g & (DI - 1);
  float Av[NS], H[NS];
  #pragma unroll
  for (int n = 0; n < NS; n++) { Av[n] = -__expf(A_log[(size_t)d * NS + n]); H[n] = 0.f; }
  for (int c = 0; c < NCHUNK; c++) {
    size_t base = ((size_t)(b * NCHUNK + c) * NS) * DI + d;
    float sd = sumd[(size_t)(b * NCHUNK + c) * DI + d];
    #pragma unroll
    for (int n = 0; n < NS; n++) {
      hin[base + (size_t)n * DI] = H[n];
      float da = __expf(Av[n] * sd);
      H[n] = da * H[n] + hend[base + (size_t)n * DI];
    }
  }
}

__global__ __launch_bounds__(256)
void scan3_kernel(const float* __restrict__ delta, const unsigned short* __restrict__ xc,
                  const float* __restrict__ dbc, const float* __restrict__ A_log,
                  const float* __restrict__ hin, const float* __restrict__ Dvec,
                  const unsigned short* __restrict__ xz, unsigned short* __restrict__ g)
{
  const int d = blockIdx.x * 256 + threadIdx.x;
  const int c = blockIdx.y;
  const int b = blockIdx.z;
  const int t0 = c * LC;
  __shared__ float bc[LC][32];
  #pragma unroll
  for (int i = 0; i < (LC * 32) / 256; i++) {
    int f = i * 256 + threadIdx.x;
    int r = f >> 5, col = f & 31;
    bc[r][col] = dbc[(size_t)(b * LSEQ + t0 + r) * 96 + 64 + col];
  }
  float Av[NS], h[NS];
  size_t base = ((size_t)(b * NCHUNK + c) * NS) * DI + d;
  #pragma unroll
  for (int n = 0; n < NS; n++) {
    Av[n] = -__expf(A_log[(size_t)d * NS + n]);
    h[n] = hin[base + (size_t)n * DI];
  }
  const float Dd = Dvec[d];
  __syncthreads();
  for (int t = 0; t < LC; t++) {
    size_t ix = (size_t)(b * LSEQ + t0 + t) * DI + d;
    float dt = delta[ix];
    float xcv = bf2f(xc[ix]);
    float dx = dt * xcv;
    float y = Dd * xcv;
    #pragma unroll
    for (int n = 0; n < NS; n++) {
      float da = __expf(dt * Av[n]);
      h[n] = da * h[n] + dx * bc[t][n];
      y += h[n] * bc[t][16 + n];
    }
    float zv = bf2f(xz[(size_t)(b * LSEQ + t0 + t) * (2 * DI) + DI + d]);
    g[ix] = f2bf(y * (zv * sigmoidf_(zv)));
  }
}

// ---------------------------------------------------------------------------
extern "C" void kernel_launch(void* const* d_in, const int* in_sizes, int n_in,
                              void* d_out, int out_size, void* d_ws, size_t ws_size,
                              hipStream_t stream)
{
  const float* x_in   = (const float*)d_in[0];
  const float* norm_w = (const float*)d_in[1];
  const float* W_in   = (const float*)d_in[2];
  const float* conv_w = (const float*)d_in[3];
  const float* conv_b = (const float*)d_in[4];
  const float* W_x    = (const float*)d_in[5];
  const float* W_dt   = (const float*)d_in[6];
  const float* b_dt   = (const float*)d_in[7];
  const float* A_log  = (const float*)d_in[8];
  const float* Dv     = (const float*)d_in[9];
  const float* W_out  = (const float*)d_in[10];
  float* x = (float*)d_out;                        // running residual stream

  char* p = (char*)d_ws;
  auto alloc = [&](size_t bytes) {
    void* r = (void*)p;
    p += (bytes + 255) & ~(size_t)255;
    return r;
  };
  unsigned short* Win_bf  = (unsigned short*)alloc((size_t)NL * 2 * DI * DM * 2);
  unsigned short* Wx_bf   = (unsigned short*)alloc((size_t)NL * 96 * DI * 2);
  unsigned short* Wdt_bf  = (unsigned short*)alloc((size_t)NL * DI * RK * 2);
  unsigned short* Wout_bf = (unsigned short*)alloc((size_t)NL * DM * DI * 2);
  unsigned short* h_bf    = (unsigned short*)alloc((size_t)MROWS * DM * 2);
  unsigned short* xz_bf   = (unsigned short*)alloc((size_t)MROWS * 2 * DI * 2);
  unsigned short* xc_bf   = (unsigned short*)alloc((size_t)MROWS * DI * 2);
  float*          dbc     = (float*)alloc((size_t)MROWS * 96 * 4);
  unsigned short* dt_bf   = (unsigned short*)alloc((size_t)MROWS * RK * 2);
  float*          delta   = (float*)alloc((size_t)MROWS * DI * 4);
  unsigned short* g_bf    = (unsigned short*)alloc((size_t)MROWS * DI * 2);
  float*          hend    = (float*)alloc((size_t)BATCH * NCHUNK * NS * DI * 4);
  float*          hin     = (float*)alloc((size_t)BATCH * NCHUNK * NS * DI * 4);
  float*          sumd    = (float*)alloc((size_t)BATCH * NCHUNK * DI * 4);

  // x = input (residual stream lives in d_out)
  hipMemcpyAsync(x, x_in, (size_t)MROWS * DM * 4, hipMemcpyDeviceToDevice, stream);

  // convert all weights (all layers, contiguous) to bf16 once per call
  f32_to_bf16_kernel<<<2048, 256, 0, stream>>>(W_in,  Win_bf,  NL * 2 * DI * DM / 4);
  f32_to_bf16_kernel<<<256,  256, 0, stream>>>(W_x,   Wx_bf,   NL * 96 * DI / 4);
  f32_to_bf16_kernel<<<256,  256, 0, stream>>>(W_dt,  Wdt_bf,  NL * DI * RK / 4);
  f32_to_bf16_kernel<<<1024, 256, 0, stream>>>(W_out, Wout_bf, NL * DM * DI / 4);

  for (int l = 0; l < NL; l++) {
    const unsigned short* Win_l  = Win_bf  + (size_t)l * 2 * DI * DM;
    const unsigned short* Wx_l   = Wx_bf   + (size_t)l * 96 * DI;
    const unsigned short* Wdt_l  = Wdt_bf  + (size_t)l * DI * RK;
    const unsigned short* Wout_l = Wout_bf + (size_t)l * DM * DI;

    rmsnorm_kernel<<<MROWS, 256, 0, stream>>>(x, norm_w + (size_t)l * DM, h_bf);

    // GEMM1: xz = h @ W_in^T   [2048, 4096], K=1024  -> bf16
    gemm_bt<128, 128, 2, 2, 0><<<dim3(MROWS / 128, (2 * DI) / 128), 256, 0, stream>>>(
        h_bf, Win_l, xz_bf, nullptr, MROWS, 2 * DI, DM, 2 * DI, 1);

    conv_silu_kernel<<<(BATCH * LSEQ * DI) / 256, 256, 0, stream>>>(
        xz_bf, conv_w + (size_t)l * DI * 4, conv_b + (size_t)l * DI, xc_bf);

    // GEMM2: dbc = xc @ W_x^T  [2048, 96], K=2048, split-K=4 atomic
    hipMemsetAsync(dbc, 0, (size_t)MROWS * 96 * 4, stream);
    gemm_bt<64, 96, 4, 1, 1><<<dim3(MROWS / 64, 1, 4), 256, 0, stream>>>(
        xc_bf, Wx_l, dbc, nullptr, MROWS, 96, DI, 96, 4);

    extract_dt_kernel<<<(MROWS * RK) / 256, 256, 0, stream>>>(dbc, dt_bf);

    // GEMM3: delta = softplus(dbc[:, :64] @ W_dt^T + b_dt)  [2048, 2048], K=64
    gemm_bt<128, 128, 2, 2, 2><<<dim3(MROWS / 128, DI / 128), 256, 0, stream>>>(
        dt_bf, Wdt_l, delta, b_dt + (size_t)l * DI, MROWS, DI, RK, DI, 1);

    // selective scan (chunked 3-phase)
    scan1_kernel<<<dim3(DI / 256, NCHUNK, BATCH), 256, 0, stream>>>(
        delta, xc_bf, dbc, A_log + (size_t)l * DI * NS, hend, sumd);
    scan2_kernel<<<(BATCH * DI) / 256, 256, 0, stream>>>(
        A_log + (size_t)l * DI * NS, hend, sumd, hin);
    scan3_kernel<<<dim3(DI / 256, NCHUNK, BATCH), 256, 0, stream>>>(
        delta, xc_bf, dbc, A_log + (size_t)l * DI * NS, hin, Dv + (size_t)l * DI, xz_bf, g_bf);

    // GEMM4: x += (y * silu(z)) @ W_out^T  [2048, 1024], K=2048
    gemm_bt<128, 128, 2, 2, 3><<<dim3(MROWS / 128, DM / 128), 256, 0, stream>>>(
        g_bf, Wout_l, x, nullptr, MROWS, DM, DI, DM, 1);
  }
}

// Round 2
// 946.113 us; speedup vs baseline: 1.2040x; 1.2040x over previous
//
#include <hip/hip_runtime.h>
#include <hip/hip_bf16.h>
#include <math.h>

#define NL 4
#define DM 1024
#define DI 2048
#define RK 64
#define NS 16
#define LSEQ 1024
#define BATCH 2
#define MROWS (BATCH*LSEQ)   // 2048 rows for all GEMMs
#define NCHUNK 32
#define LC 32                // LSEQ / NCHUNK

typedef __attribute__((ext_vector_type(8))) short bf16x8;
typedef __attribute__((ext_vector_type(4))) float f32x4;

__device__ __forceinline__ float bf2f(unsigned short u){
  union { unsigned int i; float f; } v; v.i = ((unsigned int)u) << 16; return v.f;
}
__device__ __forceinline__ unsigned short f2bf(float f){
  union { float f; unsigned int i; } v; v.f = f;
  unsigned int r = v.i + 0x7fffu + ((v.i >> 16) & 1u);  // RNE
  return (unsigned short)(r >> 16);
}
__device__ __forceinline__ float sigmoidf_(float x){ return 1.0f / (1.0f + __expf(-x)); }
__device__ __forceinline__ float softplusf_(float x){ return (x > 20.0f) ? x : log1pf(__expf(x)); }

// async 16B/lane global->LDS DMA (lds dest = wave-uniform base + lane*16)
__device__ __forceinline__ void gl2lds16(const void* g, void* l) {
  __builtin_amdgcn_global_load_lds((__attribute__((address_space(1))) void*)g,
                                   (__attribute__((address_space(3))) void*)l,
                                   16, 0, 0);
}

// ---------------------------------------------------------------------------
// Generic bf16 MFMA GEMM:  C[m,n] = sum_k A[m,k] * W[n,k]
// A row-major [M,K] bf16, W row-major [N,K] bf16 (B^T layout).
// Staging via global_load_lds dwordx4 (m97 structure): LDS tile [ROWS x 32],
// unpadded stride 32 elems (64B rows) — DMA requires lane-contiguous layout.
// EPI: 0 = store bf16; 1 = atomicAdd fp32 (split-K); 2 = softplus(acc+bias[n]) fp32;
//      3 = fp32 += (residual); 4 = store fp32
// ---------------------------------------------------------------------------
template<int BM, int BN, int WAVES_M, int WAVES_N, int EPI>
__global__ __launch_bounds__(256)
void gemm_bt(const unsigned short* __restrict__ A, const unsigned short* __restrict__ W,
             void* __restrict__ C, const float* __restrict__ bias,
             int M, int N, int K, int ldc, int kslices)
{
  constexpr int MT = BM / (WAVES_M * 16);
  constexpr int NT = BN / (WAVES_N * 16);
  __shared__ __align__(16) unsigned short As[BM * 32];
  __shared__ __align__(16) unsigned short Bs[BN * 32];

  const int tid  = threadIdx.x;
  const int wave = tid >> 6;
  const int lane = tid & 63;
  const int wm   = wave / WAVES_N;
  const int wn   = wave % WAVES_N;
  const int quad = lane >> 4;
  const int l16  = lane & 15;
  const int srow = lane >> 2;        // staging: lane -> row within 16-row chunk
  const int scol = (lane & 3) * 8;   // staging: lane -> k-col (8 bf16 = 16B)

  const int m0 = blockIdx.x * BM;
  const int n0 = blockIdx.y * BN;
  const int Ks = K / kslices;
  const int kb = blockIdx.z * Ks;

  f32x4 acc[MT][NT];
  #pragma unroll
  for (int i = 0; i < MT; i++)
    #pragma unroll
    for (int j = 0; j < NT; j++)
      acc[i][j] = (f32x4){0.f, 0.f, 0.f, 0.f};

  for (int k0 = kb; k0 < kb + Ks; k0 += 32) {
    const unsigned short* Ab = A + (size_t)m0 * K + k0;
    for (int c = wave; c < BM / 16; c += 4)
      gl2lds16(Ab + (size_t)(c * 16 + srow) * K + scol, As + c * 512);
    const unsigned short* Wb = W + (size_t)n0 * K + k0;
    for (int c = wave; c < BN / 16; c += 4)
      gl2lds16(Wb + (size_t)(c * 16 + srow) * K + scol, Bs + c * 512);
    __syncthreads();

    bf16x8 af[MT], bfr[NT];
    #pragma unroll
    for (int mt = 0; mt < MT; mt++)
      af[mt] = *(const bf16x8*)(As + (wm * MT * 16 + mt * 16 + l16) * 32 + quad * 8);
    #pragma unroll
    for (int nt = 0; nt < NT; nt++)
      bfr[nt] = *(const bf16x8*)(Bs + (wn * NT * 16 + nt * 16 + l16) * 32 + quad * 8);
    #pragma unroll
    for (int mt = 0; mt < MT; mt++)
      #pragma unroll
      for (int nt = 0; nt < NT; nt++)
        acc[mt][nt] = __builtin_amdgcn_mfma_f32_16x16x32_bf16(af[mt], bfr[nt], acc[mt][nt], 0, 0, 0);
    __syncthreads();
  }

  // epilogue: D[m][n] with m = quad*4 + r, n = l16 (verified gfx950 C/D layout)
  #pragma unroll
  for (int mt = 0; mt < MT; mt++) {
    #pragma unroll
    for (int nt = 0; nt < NT; nt++) {
      int n = n0 + wn * NT * 16 + nt * 16 + l16;
      #pragma unroll
      for (int r = 0; r < 4; r++) {
        int m = m0 + wm * MT * 16 + mt * 16 + quad * 4 + r;
        float v = acc[mt][nt][r];
        size_t off = (size_t)m * ldc + n;
        if constexpr (EPI == 0)      ((unsigned short*)C)[off] = f2bf(v);
        else if constexpr (EPI == 1) atomicAdd((float*)C + off, v);
        else if constexpr (EPI == 2) ((float*)C)[off] = softplusf_(v + bias[n]);
        else if constexpr (EPI == 3) ((float*)C)[off] += v;
        else                         ((float*)C)[off] = v;
      }
    }
  }
}

// ---------------------------------------------------------------------------
__global__ __launch_bounds__(256)
void rmsnorm_kernel(const float* __restrict__ x, const float* __restrict__ w,
                    unsigned short* __restrict__ h)
{
  const int row = blockIdx.x;
  const float4 a = ((const float4*)(x + (size_t)row * DM))[threadIdx.x];
  float ss = a.x*a.x + a.y*a.y + a.z*a.z + a.w*a.w;
  #pragma unroll
  for (int o = 32; o > 0; o >>= 1) ss += __shfl_down(ss, o);
  __shared__ float red[4];
  if ((threadIdx.x & 63) == 0) red[threadIdx.x >> 6] = ss;
  __syncthreads();
  float rs = rsqrtf((red[0] + red[1] + red[2] + red[3]) * (1.0f / DM) + 1e-5f);
  const float4 wv = ((const float4*)w)[threadIdx.x];
  ushort4 o4;
  o4.x = f2bf(a.x * rs * wv.x);
  o4.y = f2bf(a.y * rs * wv.y);
  o4.z = f2bf(a.z * rs * wv.z);
  o4.w = f2bf(a.w * rs * wv.w);
  ((ushort4*)(h + (size_t)row * DM))[threadIdx.x] = o4;
}

// causal depthwise conv (width 4) + SiLU ; xi = xz[..., :DI]
__global__ __launch_bounds__(256)
void conv_silu_kernel(const unsigned short* __restrict__ xz,
                      const float* __restrict__ cw, const float* __restrict__ cb,
                      unsigned short* __restrict__ xc)
{
  int idx = blockIdx.x * 256 + threadIdx.x;        // [B, L, DI]
  int d = idx & (DI - 1);
  int t = (idx >> 11) & (LSEQ - 1);
  int b = idx >> 21;
  const float4 w4 = ((const float4*)cw)[d];
  const float wk[4] = {w4.x, w4.y, w4.z, w4.w};
  const unsigned short* xi = xz + (size_t)b * LSEQ * (2 * DI) + d;
  float acc = cb[d];
  #pragma unroll
  for (int k = 0; k < 4; k++) {
    int tt = t - 3 + k;
    if (tt >= 0) acc += bf2f(xi[(size_t)tt * (2 * DI)]) * wk[k];
  }
  xc[idx] = f2bf(acc * sigmoidf_(acc));
}

// dbc[:, :64] -> bf16 A-matrix for GEMM3
__global__ __launch_bounds__(256)
void extract_dt_kernel(const float* __restrict__ dbc, unsigned short* __restrict__ out)
{
  int idx = blockIdx.x * 256 + threadIdx.x;        // MROWS*RK
  int m = idx >> 6, r = idx & 63;
  out[idx] = f2bf(dbc[(size_t)m * 96 + r]);
}

__global__ void f32_to_bf16_kernel(const float* __restrict__ s, unsigned short* __restrict__ d, int n4)
{
  int i = blockIdx.x * 256 + threadIdx.x;
  int stride = gridDim.x * 256;
  for (; i < n4; i += stride) {
    float4 v = ((const float4*)s)[i];
    ushort4 o; o.x = f2bf(v.x); o.y = f2bf(v.y); o.z = f2bf(v.z); o.w = f2bf(v.w);
    ((ushort4*)d)[i] = o;
  }
}

// ---------------------------------------------------------------------------
// Chunked selective scan.  State layout for hend/hin: [b][chunk][n][d] (coalesced in d)
// ---------------------------------------------------------------------------
__global__ __launch_bounds__(256)
void scan1_kernel(const float* __restrict__ delta, const unsigned short* __restrict__ xc,
                  const float* __restrict__ dbc, const float* __restrict__ A_log,
                  float* __restrict__ hend, float* __restrict__ sumd)
{
  const int d = blockIdx.x * 256 + threadIdx.x;
  const int c = blockIdx.y;
  const int b = blockIdx.z;
  const int t0 = c * LC;
  __shared__ float bc[LC][32];                     // cols 0..15 = B, 16..31 = C
  #pragma unroll
  for (int i = 0; i < (LC * 32) / 256; i++) {
    int f = i * 256 + threadIdx.x;
    int r = f >> 5, col = f & 31;
    bc[r][col] = dbc[(size_t)(b * LSEQ + t0 + r) * 96 + 64 + col];
  }
  float Av[NS], h[NS];
  #pragma unroll
  for (int n = 0; n < NS; n++) { Av[n] = -__expf(A_log[(size_t)d * NS + n]); h[n] = 0.f; }
  __syncthreads();
  float sd = 0.f;
  for (int t = 0; t < LC; t++) {
    size_t ix = (size_t)(b * LSEQ + t0 + t) * DI + d;
    float dt = delta[ix];
    float xcv = bf2f(xc[ix]);
    sd += dt;
    float dx = dt * xcv;
    #pragma unroll
    for (int n = 0; n < NS; n++) {
      float da = __expf(dt * Av[n]);
      h[n] = da * h[n] + dx * bc[t][n];
    }
  }
  size_t base = ((size_t)(b * NCHUNK + c) * NS) * DI + d;
  #pragma unroll
  for (int n = 0; n < NS; n++) hend[base + (size_t)n * DI] = h[n];
  sumd[(size_t)(b * NCHUNK + c) * DI + d] = sd;
}

__global__ __launch_bounds__(256)
void scan2_kernel(const float* __restrict__ A_log, const float* __restrict__ hend,
                  const float* __restrict__ sumd, float* __restrict__ hin)
{
  int g = blockIdx.x * 256 + threadIdx.x;          // BATCH*DI threads
  int b = g >> 11;
  int d = g & (DI - 1);
  float Av[NS], H[NS];
  #pragma unroll
  for (int n = 0; n < NS; n++) { Av[n] = -__expf(A_log[(size_t)d * NS + n]); H[n] = 0.f; }
  for (int c = 0; c < NCHUNK; c++) {
    size_t base = ((size_t)(b * NCHUNK + c) * NS) * DI + d;
    float sd = sumd[(size_t)(b * NCHUNK + c) * DI + d];
    #pragma unroll
    for (int n = 0; n < NS; n++) {
      hin[base + (size_t)n * DI] = H[n];
      float da = __expf(Av[n] * sd);
      H[n] = da * H[n] + hend[base + (size_t)n * DI];
    }
  }
}

__global__ __launch_bounds__(256)
void scan3_kernel(const float* __restrict__ delta, const unsigned short* __restrict__ xc,
                  const float* __restrict__ dbc, const float* __restrict__ A_log,
                  const float* __restrict__ hin, const float* __restrict__ Dvec,
                  const unsigned short* __restrict__ xz, unsigned short* __restrict__ g)
{
  const int d = blockIdx.x * 256 + threadIdx.x;
  const int c = blockIdx.y;
  const int b = blockIdx.z;
  const int t0 = c * LC;
  __shared__ float bc[LC][32];
  #pragma unroll
  for (int i = 0; i < (LC * 32) / 256; i++) {
    int f = i * 256 + threadIdx.x;
    int r = f >> 5, col = f & 31;
    bc[r][col] = dbc[(size_t)(b * LSEQ + t0 + r) * 96 + 64 + col];
  }
  float Av[NS], h[NS];
  size_t base = ((size_t)(b * NCHUNK + c) * NS) * DI + d;
  #pragma unroll
  for (int n = 0; n < NS; n++) {
    Av[n] = -__expf(A_log[(size_t)d * NS + n]);
    h[n] = hin[base + (size_t)n * DI];
  }
  const float Dd = Dvec[d];
  __syncthreads();
  for (int t = 0; t < LC; t++) {
    size_t ix = (size_t)(b * LSEQ + t0 + t) * DI + d;
    float dt = delta[ix];
    float xcv = bf2f(xc[ix]);
    float dx = dt * xcv;
    float y = Dd * xcv;
    #pragma unroll
    for (int n = 0; n < NS; n++) {
      float da = __expf(dt * Av[n]);
      h[n] = da * h[n] + dx * bc[t][n];
      y += h[n] * bc[t][16 + n];
    }
    float zv = bf2f(xz[(size_t)(b * LSEQ + t0 + t) * (2 * DI) + DI + d]);
    g[ix] = f2bf(y * (zv * sigmoidf_(zv)));
  }
}

// ---------------------------------------------------------------------------
extern "C" void kernel_launch(void* const* d_in, const int* in_sizes, int n_in,
                              void* d_out, int out_size, void* d_ws, size_t ws_size,
                              hipStream_t stream)
{
  const float* x_in   = (const float*)d_in[0];
  const float* norm_w = (const float*)d_in[1];
  const float* W_in   = (const float*)d_in[2];
  const float* conv_w = (const float*)d_in[3];
  const float* conv_b = (const float*)d_in[4];
  const float* W_x    = (const float*)d_in[5];
  const float* W_dt   = (const float*)d_in[6];
  const float* b_dt   = (const float*)d_in[7];
  const float* A_log  = (const float*)d_in[8];
  const float* Dv     = (const float*)d_in[9];
  const float* W_out  = (const float*)d_in[10];
  float* x = (float*)d_out;                        // running residual stream

  char* p = (char*)d_ws;
  auto alloc = [&](size_t bytes) {
    void* r = (void*)p;
    p += (bytes + 255) & ~(size_t)255;
    return r;
  };
  unsigned short* Win_bf  = (unsigned short*)alloc((size_t)NL * 2 * DI * DM * 2);
  unsigned short* Wx_bf   = (unsigned short*)alloc((size_t)NL * 96 * DI * 2);
  unsigned short* Wdt_bf  = (unsigned short*)alloc((size_t)NL * DI * RK * 2);
  unsigned short* Wout_bf = (unsigned short*)alloc((size_t)NL * DM * DI * 2);
  unsigned short* h_bf    = (unsigned short*)alloc((size_t)MROWS * DM * 2);
  unsigned short* xz_bf   = (unsigned short*)alloc((size_t)MROWS * 2 * DI * 2);
  unsigned short* xc_bf   = (unsigned short*)alloc((size_t)MROWS * DI * 2);
  float*          dbc     = (float*)alloc((size_t)MROWS * 96 * 4);
  unsigned short* dt_bf   = (unsigned short*)alloc((size_t)MROWS * RK * 2);
  float*          delta   = (float*)alloc((size_t)MROWS * DI * 4);
  unsigned short* g_bf    = (unsigned short*)alloc((size_t)MROWS * DI * 2);
  float*          hend    = (float*)alloc((size_t)BATCH * NCHUNK * NS * DI * 4);
  float*          hin     = (float*)alloc((size_t)BATCH * NCHUNK * NS * DI * 4);
  float*          sumd    = (float*)alloc((size_t)BATCH * NCHUNK * DI * 4);

  // x = input (residual stream lives in d_out)
  hipMemcpyAsync(x, x_in, (size_t)MROWS * DM * 4, hipMemcpyDeviceToDevice, stream);

  // convert all weights (all layers, contiguous) to bf16 once per call
  f32_to_bf16_kernel<<<2048, 256, 0, stream>>>(W_in,  Win_bf,  NL * 2 * DI * DM / 4);
  f32_to_bf16_kernel<<<256,  256, 0, stream>>>(W_x,   Wx_bf,   NL * 96 * DI / 4);
  f32_to_bf16_kernel<<<256,  256, 0, stream>>>(W_dt,  Wdt_bf,  NL * DI * RK / 4);
  f32_to_bf16_kernel<<<1024, 256, 0, stream>>>(W_out, Wout_bf, NL * DM * DI / 4);

  for (int l = 0; l < NL; l++) {
    const unsigned short* Win_l  = Win_bf  + (size_t)l * 2 * DI * DM;
    const unsigned short* Wx_l   = Wx_bf   + (size_t)l * 96 * DI;
    const unsigned short* Wdt_l  = Wdt_bf  + (size_t)l * DI * RK;
    const unsigned short* Wout_l = Wout_bf + (size_t)l * DM * DI;

    rmsnorm_kernel<<<MROWS, 256, 0, stream>>>(x, norm_w + (size_t)l * DM, h_bf);

    // GEMM1: xz = h @ W_in^T   [2048, 4096], K=1024  -> bf16
    gemm_bt<128, 128, 2, 2, 0><<<dim3(MROWS / 128, (2 * DI) / 128), 256, 0, stream>>>(
        h_bf, Win_l, xz_bf, nullptr, MROWS, 2 * DI, DM, 2 * DI, 1);

    conv_silu_kernel<<<(BATCH * LSEQ * DI) / 256, 256, 0, stream>>>(
        xz_bf, conv_w + (size_t)l * DI * 4, conv_b + (size_t)l * DI, xc_bf);

    // GEMM2: dbc = xc @ W_x^T  [2048, 96], K=2048, split-K=4 atomic
    hipMemsetAsync(dbc, 0, (size_t)MROWS * 96 * 4, stream);
    gemm_bt<64, 96, 4, 1, 1><<<dim3(MROWS / 64, 1, 4), 256, 0, stream>>>(
        xc_bf, Wx_l, dbc, nullptr, MROWS, 96, DI, 96, 4);

    extract_dt_kernel<<<(MROWS * RK) / 256, 256, 0, stream>>>(dbc, dt_bf);

    // GEMM3: delta = softplus(dbc[:, :64] @ W_dt^T + b_dt)  [2048, 2048], K=64
    gemm_bt<128, 128, 2, 2, 2><<<dim3(MROWS / 128, DI / 128), 256, 0, stream>>>(
        dt_bf, Wdt_l, delta, b_dt + (size_t)l * DI, MROWS, DI, RK, DI, 1);

    // selective scan (chunked 3-phase)
    scan1_kernel<<<dim3(DI / 256, NCHUNK, BATCH), 256, 0, stream>>>(
        delta, xc_bf, dbc, A_log + (size_t)l * DI * NS, hend, sumd);
    scan2_kernel<<<(BATCH * DI) / 256, 256, 0, stream>>>(
        A_log + (size_t)l * DI * NS, hend, sumd, hin);
    scan3_kernel<<<dim3(DI / 256, NCHUNK, BATCH), 256, 0, stream>>>(
        delta, xc_bf, dbc, A_log + (size_t)l * DI * NS, hin, Dv + (size_t)l * DI, xz_bf, g_bf);

    // GEMM4: x += (y * silu(z)) @ W_out^T  [2048, 1024], K=2048, split-K=4 atomic into x
    gemm_bt<128, 128, 2, 2, 1><<<dim3(MROWS / 128, DM / 128, 4), 256, 0, stream>>>(
        g_bf, Wout_l, x, nullptr, MROWS, DM, DI, DM, 4);
  }
}